// Round 10
// baseline (293.186 us; speedup 1.0000x reference)
//
#include <hip/hip_runtime.h>

#define PTOT   1048576
#define NRAYS  8192
#define THRESH 1e-4f

typedef float F2 __attribute__((ext_vector_type(2)));

__device__ __forceinline__ F2 f2splat(float s){ F2 r; r.x = s; r.y = s; return r; }
__device__ __forceinline__ F2 f2fma(F2 a, float b, F2 c){
    return __builtin_elementwise_fma(a, f2splat(b), c);
}
// packed fp32 FMA, weight broadcast pair in SGPRs (VOP3P, gfx90a+).
// NOTE: v_pk_max_f32 does NOT exist on gfx950 (R9 compile fail) — relu is done
// with two scalar v_max_f32 via __builtin_elementwise_max instead.
__device__ __forceinline__ F2 pkfma(F2 a, F2 w, F2 c){
    F2 d;
    asm("v_pk_fma_f32 %0, %1, %2, %3" : "=v"(d) : "v"(a), "s"(w), "v"(c));
    return d;
}
__device__ __forceinline__ float raw2alpha_f(float d){
    // 1 - exp(-softplus(d - 4) * 0.5) == 1 - (1 + e^(d-4))^(-1/2)
    return 1.0f - rsqrtf(1.0f + __expf(d - 4.0f));
}

// ---------------- kernel 1: density alpha + gate + vd cache + ray_off ----------------
__global__ __launch_bounds__(256) void k_point(
    const float* __restrict__ pts, const float* __restrict__ vdirs,
    const int* __restrict__ ray_id,
    const float* __restrict__ Wd1, const float* __restrict__ bd1,
    const float* __restrict__ Wd2, const float* __restrict__ Wg,
    float* __restrict__ alpha0, float* __restrict__ g0a, int* __restrict__ eea,
    float4* __restrict__ vd, int* __restrict__ ray_off)
{
    __shared__ float4 WD4[128];   // {Wd1[0][i], Wd1[1][i], Wd1[2][i], bd1[i]}
    __shared__ float  WD2s[128];
    __shared__ float  WGs[8][6];
    int t = threadIdx.x;
    if (t < 128){
        WD4[t] = make_float4(Wd1[t], Wd1[128+t], Wd1[256+t], bd1[t]);
        WD2s[t] = Wd2[t];
    }
    if (t < 48) WGs[t & 7][t >> 3] = Wg[t];   // Wg[k][e] flat = k*8+e
    __syncthreads();

    int base = blockIdx.x * 2048 + t;         // 8 points/thread as 4 F2 pairs
    F2 px[4], py[4], pz[4], vx[4], vy[4], vz[4], dens[4];
    int rid0[4], rid1[4];
    #pragma unroll
    for (int q=0;q<4;q++){
        int p0 = base + (2*q)*256, p1 = p0 + 256;
        px[q] = (F2){pts[3*p0],   pts[3*p1]};
        py[q] = (F2){pts[3*p0+1], pts[3*p1+1]};
        pz[q] = (F2){pts[3*p0+2], pts[3*p1+2]};
        int r0 = ray_id[p0], r1 = ray_id[p1];
        rid0[q] = r0; rid1[q] = r1;
        vx[q] = (F2){vdirs[3*r0],   vdirs[3*r1]};
        vy[q] = (F2){vdirs[3*r0+1], vdirs[3*r1+1]};
        vz[q] = (F2){vdirs[3*r0+2], vdirs[3*r1+2]};
        dens[q] = f2splat(0.f);
    }
    // vd cache (one coalesced float4 per point) + ray segment boundaries
    #pragma unroll
    for (int q=0;q<4;q++){
        int p0 = base + (2*q)*256, p1 = p0 + 256;
        vd[p0] = make_float4(vx[q].x, vy[q].x, vz[q].x, 0.f);
        vd[p1] = make_float4(vx[q].y, vy[q].y, vz[q].y, 0.f);
        int prev0 = (p0 == 0) ? -1 : ray_id[p0-1];
        if (prev0 != rid0[q]) for (int r=prev0+1; r<=rid0[q]; ++r) ray_off[r] = p0;
        int prev1 = ray_id[p1-1];
        if (prev1 != rid1[q]) for (int r=prev1+1; r<=rid1[q]; ++r) ray_off[r] = p1;
        if (p1 == PTOT-1) for (int r=rid1[q]+1; r<=NRAYS; ++r) ray_off[r] = PTOT;
    }
    #pragma unroll 2
    for (int i=0;i<128;i++){
        float4 w = WD4[i]; float w2 = WD2s[i];
        #pragma unroll
        for (int q=0;q<4;q++){
            F2 h = f2fma(px[q], w.x, f2fma(py[q], w.y, f2fma(pz[q], w.z, f2splat(w.w))));
            h = __builtin_elementwise_max(h, f2splat(0.f));
            dens[q] = f2fma(h, w2, dens[q]);
        }
    }
    #pragma unroll
    for (int q=0;q<4;q++){
        float a0 = raw2alpha_f(dens[q].x);
        float a1 = raw2alpha_f(dens[q].y);
        alpha0[base + (2*q)*256]   = (a0 > THRESH) ? a0 : 0.f;
        alpha0[base + (2*q+1)*256] = (a1 > THRESH) ? a1 : 0.f;
    }
    // gate: top-2 of softmax over 8 experts, renormalized
    float m0[8], m1[8]; int i0[8], i1[8];
    #pragma unroll
    for (int j=0;j<8;j++){ m0[j]=-3.0e38f; m1[j]=-3.0e38f; i0[j]=0; i1[j]=0; }
    for (int e=0;e<8;e++){
        float w0=WGs[e][0],w1=WGs[e][1],w2=WGs[e][2],w3=WGs[e][3],w4=WGs[e][4],w5=WGs[e][5];
        #pragma unroll
        for (int q=0;q<4;q++){
            F2 l = f2fma(px[q],w0, f2fma(py[q],w1, f2fma(pz[q],w2,
                   f2fma(vx[q],w3, f2fma(vy[q],w4,
                   __builtin_elementwise_fma(vz[q], f2splat(w5), f2splat(0.f)))))));
            int j0 = 2*q, j1 = 2*q+1;
            float lx = l.x, ly = l.y;
            if (lx > m0[j0]){ m1[j0]=m0[j0]; i1[j0]=i0[j0]; m0[j0]=lx; i0[j0]=e; }
            else if (lx > m1[j0]){ m1[j0]=lx; i1[j0]=e; }
            if (ly > m0[j1]){ m1[j1]=m0[j1]; i1[j1]=i0[j1]; m0[j1]=ly; i0[j1]=e; }
            else if (ly > m1[j1]){ m1[j1]=ly; i1[j1]=e; }
        }
    }
    #pragma unroll
    for (int j=0;j<8;j++){
        float g0 = __fdividef(1.0f, 1.0f + __expf(m1[j]-m0[j]));
        g0a[base + j*256] = g0;
        eea[base + j*256] = i0[j] | (i1[j] << 8);
    }
}

// ---------------- kernel 1b: duplicate expert weights into {w,w} pairs ----------------
// wdup[(e*128+i)*12 + k]: k=0..5 We1 cols, 6 bias, 7..9 Wrgb rows, 10 Walpha
__global__ __launch_bounds__(128) void k_prep(
    const float* __restrict__ We1, const float* __restrict__ be1,
    const float* __restrict__ Wrgb, const float* __restrict__ Walpha,
    F2* __restrict__ wdup)
{
    int e = blockIdx.x, i = threadIdx.x;
    F2* d = wdup + (e*128 + i)*12;
    const float* w = We1 + e*768;
    #pragma unroll
    for (int j=0;j<6;j++){ float v = w[j*128+i]; d[j] = (F2){v,v}; }
    float b  = be1[e*128+i];        d[6]  = (F2){b,b};
    float r0 = Wrgb[e*384+3*i+0];   d[7]  = (F2){r0,r0};
    float r1 = Wrgb[e*384+3*i+1];   d[8]  = (F2){r1,r1};
    float r2 = Wrgb[e*384+3*i+2];   d[9]  = (F2){r2,r2};
    float wa = Walpha[e*128+i];     d[10] = (F2){wa,wa};
    d[11] = (F2){0.f,0.f};
}

// ---------------- kernel 2: transmittance scan -> keep mask + expert counts ----------------
__global__ __launch_bounds__(256) void k_scan0(const float* __restrict__ alpha0,
                                               const int* __restrict__ eea,
                                               const int* __restrict__ ray_off,
                                               unsigned char* __restrict__ keep,
                                               int* __restrict__ cntA)
{
    __shared__ int wcs[4][8];
    int t = threadIdx.x, lane = t & 63, w = t >> 6;
    int wid = blockIdx.x*4 + w;                      // wave = ray
    int c[8];
    #pragma unroll
    for (int e=0;e<8;e++) c[e]=0;
    int s = ray_off[wid], e = ray_off[wid+1];
    float carry = 1.f;
    for (int ch = s; ch < e; ch += 64){
        int p = ch + lane;
        bool in = p < e;
        float a = in ? alpha0[p] : 0.f;
        int  ee = in ? eea[p] : 0;
        float incl = 1.f - a;
        #pragma unroll
        for (int d=1; d<64; d<<=1){ float tt = __shfl_up(incl, d); if (lane >= d) incl *= tt; }
        float excl = __shfl_up(incl, 1); if (lane == 0) excl = 1.f;
        float w0 = a * carry * excl;
        int k = (in && w0 > THRESH) ? 1 : 0;
        if (in) keep[p] = (unsigned char)k;
        int e0 = ee & 255, e1 = (ee >> 8) & 255;
        #pragma unroll
        for (int x=0;x<8;x++){
            unsigned long long m0 = __ballot(k && e0==x);
            unsigned long long m1 = __ballot(k && e1==x);
            c[x] += __popcll(m0) + __popcll(m1);
        }
        carry *= __shfl(incl, 63);
    }
    if (lane == 0){
        #pragma unroll
        for (int x=0;x<8;x++) wcs[w][x] = c[x];
    }
    __syncthreads();
    if (t < 8){
        int sum = wcs[0][t]+wcs[1][t]+wcs[2][t]+wcs[3][t];
        if (sum) atomicAdd(&cntA[t], sum);
    }
}

// ---------------- kernel 3: fill entries (ballot-ranked; local prefix of cntA) ----------------
// entry.x = pid | (slot << 30), entry.y = gate weight bits
__global__ __launch_bounds__(256) void k_fill(const unsigned char* __restrict__ keep,
                                              const float* __restrict__ g0a,
                                              const int* __restrict__ eea,
                                              const int* __restrict__ cntA,
                                              int* __restrict__ curA,
                                              int2* __restrict__ ent)
{
    __shared__ int wc[4][8];
    __shared__ int wb[4][8];
    __shared__ int sOff[8];
    int t = threadIdx.x, lane = t & 63, w = t >> 6;
    unsigned long long lt = (1ull << lane) - 1ull;
    int base = blockIdx.x * 2048;

    int c[8];
    #pragma unroll
    for (int e=0;e<8;e++) c[e]=0;
    for (int j=0;j<8;j++){
        int p = base + (j*4 + w)*64 + lane;
        int k = keep[p];
        int ee = eea[p];
        int e0 = ee & 255, e1 = (ee >> 8) & 255;
        #pragma unroll
        for (int e=0;e<8;e++){
            unsigned long long m0 = __ballot(k && e0==e);
            unsigned long long m1 = __ballot(k && e1==e);
            c[e] += __popcll(m0) + __popcll(m1);
        }
    }
    if (lane == 0){
        #pragma unroll
        for (int e=0;e<8;e++) wc[w][e] = c[e];
    }
    if (t == 0){                                // local exclusive prefix of cntA
        int acc = 0;
        for (int e=0;e<8;e++){ sOff[e] = acc; acc += cntA[e]; }
    }
    __syncthreads();
    if (t < 8){
        int tot = wc[0][t]+wc[1][t]+wc[2][t]+wc[3][t];
        int b = sOff[t] + (tot ? atomicAdd(&curA[t], tot) : 0);
        wb[0][t] = b; b += wc[0][t];
        wb[1][t] = b; b += wc[1][t];
        wb[2][t] = b; b += wc[2][t];
        wb[3][t] = b;
    }
    __syncthreads();

    int cur[8];
    #pragma unroll
    for (int e=0;e<8;e++) cur[e] = wb[w][e];
    for (int j=0;j<8;j++){
        int p = base + (j*4 + w)*64 + lane;
        int k = keep[p];
        float g0 = g0a[p];
        int ee = eea[p];
        int e0 = ee & 255, e1 = (ee >> 8) & 255;
        #pragma unroll
        for (int e=0;e<8;e++){
            unsigned long long m0 = __ballot(k && e0==e);
            unsigned long long m1 = __ballot(k && e1==e);
            if (k && e0==e)
                ent[cur[e] + __popcll(m0 & lt)] = make_int2(p, __float_as_int(g0));
            if (k && e1==e)
                ent[cur[e] + __popcll(m0) + __popcll(m1 & lt)] =
                    make_int2(p | (1 << 30), __float_as_int(1.0f - g0));
            cur[e] += __popcll(m0) + __popcll(m1);
        }
    }
}

// ---------------- kernel 4: expert MLPs (explicit v_pk_fma_f32, SGPR weights) ----------------
// 512 blocks/expert, 256 threads, 4 F2 pairs/thread. Weights read via uniform
// s_load as pre-duplicated {w,w} SGPR pairs -> v_pk_fma_f32 with no LDS, no movs.
// NOTE: live state ~80 VGPRs max — 16 entries/thread spilled in R4. MFMA (R7)
// was slower at this GEMM shape. Builtin elementwise fma scalarizes (R8: 61
// cyc/entry vs 22 theoretical) — hence explicit asm. relu = 2x v_max_f32
// (v_pk_max_f32 doesn't exist on gfx950).
__global__ __launch_bounds__(256) void k_expert(
    const int2* __restrict__ ent, const int* __restrict__ cntA,
    const F2* __restrict__ wdup,
    const float* __restrict__ pts, const float4* __restrict__ vd,
    float4* __restrict__ res)
{
    int e    = blockIdx.x >> 9;
    int bi   = blockIdx.x & 511;
    int base = bi * 2048;

    __shared__ int sSeg[2];      // {segment start, n}
    int t = threadIdx.x;
    if (t == 0){
        int acc = 0;
        for (int i=0;i<e;i++) acc += cntA[i];
        sSeg[0] = acc; sSeg[1] = cntA[e];
    }
    __syncthreads();
    int n = sSeg[1];
    if (base >= n) return;                      // uniform exit (post-barrier)
    const int2* eb = ent + sSeg[0];

    F2 x0[4],x1[4],x2[4],x3[4],x4[4],x5[4];
    F2 ar[4],ag[4],ab[4],aa[4];
    #pragma unroll
    for (int pr=0;pr<4;pr++){
        int idx0 = base + t + (2*pr)*256, idx1 = idx0 + 256;
        int2 r0 = (idx0 < n) ? eb[idx0] : make_int2(0,0);
        int2 r1 = (idx1 < n) ? eb[idx1] : make_int2(0,0);
        int p0 = r0.x & 0x0FFFFFFF, p1 = r1.x & 0x0FFFFFFF;
        x0[pr] = (F2){pts[3*p0],   pts[3*p1]};
        x1[pr] = (F2){pts[3*p0+1], pts[3*p1+1]};
        x2[pr] = (F2){pts[3*p0+2], pts[3*p1+2]};
        float4 v0 = vd[p0], v1 = vd[p1];
        x3[pr] = (F2){v0.x, v1.x};
        x4[pr] = (F2){v0.y, v1.y};
        x5[pr] = (F2){v0.z, v1.z};
        ar[pr] = f2splat(0.f); ag[pr] = f2splat(0.f);
        ab[pr] = f2splat(0.f); aa[pr] = f2splat(0.f);
    }
    F2 zz = f2splat(0.f);
    const F2* wd = wdup + e*128*12;
    #pragma unroll 2
    for (int i=0;i<128;i++){
        const F2* wi = wd + i*12;
        F2 w0=wi[0], w1=wi[1], w2=wi[2], w3=wi[3], w4=wi[4], w5=wi[5], bb=wi[6];
        F2 c0=wi[7], c1=wi[8], c2=wi[9], ca=wi[10];
        #pragma unroll
        for (int pr=0;pr<4;pr++){
            F2 h = pkfma(x5[pr], w5, bb);
            h = pkfma(x4[pr], w4, h);
            h = pkfma(x3[pr], w3, h);
            h = pkfma(x2[pr], w2, h);
            h = pkfma(x1[pr], w1, h);
            h = pkfma(x0[pr], w0, h);
            h = __builtin_elementwise_max(h, zz);   // 2x v_max_f32
            ar[pr] = pkfma(h, c0, ar[pr]);
            ag[pr] = pkfma(h, c1, ag[pr]);
            ab[pr] = pkfma(h, c2, ab[pr]);
            aa[pr] = pkfma(h, ca, aa[pr]);
        }
    }
    #pragma unroll
    for (int pr=0;pr<4;pr++){
        #pragma unroll
        for (int sel=0; sel<2; sel++){
            int idx = base + t + (2*pr+sel)*256;
            if (idx < n){
                int2 rec = eb[idx];                 // reload g/pid (keeps loop VGPRs low)
                float vr = sel ? ar[pr].y : ar[pr].x;
                float vg = sel ? ag[pr].y : ag[pr].x;
                float vb = sel ? ab[pr].y : ab[pr].x;
                float va = sel ? aa[pr].y : aa[pr].x;
                float sr = __fdividef(1.0f, 1.0f + __expf(-vr));
                float sg = __fdividef(1.0f, 1.0f + __expf(-vg));
                float sb = __fdividef(1.0f, 1.0f + __expf(-vb));
                float a  = raw2alpha_f(va);
                float g  = __int_as_float(rec.y);
                int pp   = rec.x & 0x0FFFFFFF;
                int slot = ((unsigned)rec.x) >> 30;
                res[2*(size_t)pp + slot] = make_float4(g*sr, g*sg, g*sb, g*a);
            }
        }
    }
}

// ---------------- kernel 5: final per-ray composite ----------------
__global__ __launch_bounds__(256) void k_scan1(const float4* __restrict__ res,
                                               const unsigned char* __restrict__ keep,
                                               const int* __restrict__ ray_off,
                                               const float* __restrict__ bg,
                                               float* __restrict__ out)
{
    int wid  = (blockIdx.x*blockDim.x + threadIdx.x) >> 6;   // wave = ray
    int lane = threadIdx.x & 63;
    if (wid >= NRAYS) return;
    int s = ray_off[wid], e = ray_off[wid+1];
    float carry = 1.f;
    float accx = 0.f, accy = 0.f, accz = 0.f;
    for (int c = s; c < e; c += 64){
        int p = c + lane;
        float4 v = make_float4(0.f,0.f,0.f,0.f);
        if (p < e && keep[p]){
            float4 v0 = res[2*(size_t)p];
            float4 v1 = res[2*(size_t)p + 1];
            v = make_float4(v0.x+v1.x, v0.y+v1.y, v0.z+v1.z, v0.w+v1.w);
        }
        float a = v.w;
        float incl = 1.f - a;
        #pragma unroll
        for (int d=1; d<64; d<<=1){ float tt = __shfl_up(incl, d); if (lane >= d) incl *= tt; }
        float excl = __shfl_up(incl, 1); if (lane == 0) excl = 1.f;
        float w = a * carry * excl;
        accx = fmaf(w, v.x, accx);
        accy = fmaf(w, v.y, accy);
        accz = fmaf(w, v.z, accz);
        carry *= __shfl(incl, 63);
    }
    #pragma unroll
    for (int d=32; d; d>>=1){
        accx += __shfl_xor(accx, d);
        accy += __shfl_xor(accy, d);
        accz += __shfl_xor(accz, d);
    }
    if (lane == 0){
        out[3*wid+0] = accx + carry*bg[0];
        out[3*wid+1] = accy + carry*bg[1];
        out[3*wid+2] = accz + carry*bg[2];
    }
}

extern "C" void kernel_launch(void* const* d_in, const int* in_sizes, int n_in,
                              void* d_out, int out_size, void* d_ws, size_t ws_size,
                              hipStream_t stream)
{
    const float* pts    = (const float*)d_in[0];
    const float* vdirs  = (const float*)d_in[1];
    const float* bg     = (const float*)d_in[2];
    const float* Wd1    = (const float*)d_in[3];
    const float* bd1    = (const float*)d_in[4];
    const float* Wd2    = (const float*)d_in[5];
    const float* Wg     = (const float*)d_in[6];
    const float* We1    = (const float*)d_in[7];
    const float* be1    = (const float*)d_in[8];
    const float* Wrgb   = (const float*)d_in[9];
    const float* Walpha = (const float*)d_in[10];
    const int*   ray_id = (const int*)d_in[11];
    float* out = (float*)d_out;

    char* ws = (char*)d_ws;
    size_t off = 0;
    float* alpha0        = (float*)(ws + off); off += (size_t)PTOT*4;       // 4MB
    float* g0a           = (float*)(ws + off); off += (size_t)PTOT*4;       // 4MB
    int*   eea           = (int*)  (ws + off); off += (size_t)PTOT*4;       // 4MB
    unsigned char* keep  = (unsigned char*)(ws + off); off += (size_t)PTOT; // 1MB
    int*   ray_off       = (int*)  (ws + off); off += 33024;                // 8193+ ints
    int*   cntA          = (int*)  (ws + off); off += 256;
    int*   curA          = (int*)  (ws + off); off += 256;
    off = (off + 255) & ~(size_t)255;
    F2*    wdup          = (F2*)   (ws + off); off += 8*128*12*8;           // 96KB
    off = (off + 255) & ~(size_t)255;
    float4* vd           = (float4*)(ws + off); off += (size_t)PTOT*16;     // 16MB
    int2*  ent           = (int2*) (ws + off); off += (size_t)2*PTOT*8;     // 16MB
    float4* res          = (float4*)(ws + off); off += ((size_t)2*PTOT+2)*16; // 32MB

    hipMemsetAsync(cntA, 0, 512, stream);   // cntA + curA (adjacent)

    k_point <<<PTOT/2048, 256, 0, stream>>>(pts, vdirs, ray_id, Wd1, bd1, Wd2, Wg,
                                            alpha0, g0a, eea, vd, ray_off);
    k_prep  <<<8, 128, 0, stream>>>(We1, be1, Wrgb, Walpha, wdup);
    k_scan0 <<<NRAYS/4, 256, 0, stream>>>(alpha0, eea, ray_off, keep, cntA);
    k_fill  <<<PTOT/2048, 256, 0, stream>>>(keep, g0a, eea, cntA, curA, ent);
    k_expert<<<8*512, 256, 0, stream>>>(ent, cntA, wdup, pts, vd, res);
    k_scan1 <<<NRAYS*64/256, 256, 0, stream>>>(res, keep, ray_off, bg, out);
}